// Round 1
// baseline (78992.334 us; speedup 1.0000x reference)
//
#include <hip/hip_runtime.h>
#include <hip/hip_cooperative_groups.h>

namespace cg = cooperative_groups;

#define BB 128      // batch
#define TT 1024     // seq len
#define II 64       // input size
#define HH 512      // hidden
#define KK 576      // II + HH
#define NBLK 256    // one block per pair of h-columns
#define NTHR 256

// Persistent cooperative LSTM.
// Block g owns h-columns {2g, 2g+1} -> 8 rows of [W_ih | W_hh] resident in LDS.
// Per step: stage full [x_t | h_prev] (transposed-free: [b][k] chunks) in LDS,
// each thread computes a (2 rows x 2 batch) tile of gate dots (float4),
// update c (block-private, LDS) and h (global, double-buffered), grid.sync.
// y[b,t] = W_fc . h_t computed by block 0 from the h it stages next step.
__global__ __launch_bounds__(NTHR, 1)
void lstm_persist(const float* __restrict__ x,
                  const float* __restrict__ W_ih,
                  const float* __restrict__ W_hh,
                  const float* __restrict__ b_ih,
                  const float* __restrict__ b_hh,
                  const float* __restrict__ W_fc,
                  const float* __restrict__ b_fc,
                  float* __restrict__ out,
                  float* __restrict__ hbuf /* 2 x [128][512] f32 */)
{
    __shared__ float Wl[8][KK];      // rows: gate*2 + jj  (i,i,f,f,g,g,o,o)
    __shared__ float vx[BB][68];     // one 64-k chunk of [x_t|h], pad 68 (bank-safe)
    __shared__ float gl[8][BB];      // gate dot results
    __shared__ float cl[2][BB];      // cell state (block-private, persistent)
    __shared__ float yl[2][BB];      // y partials (block 0 only)
    __shared__ float wfc[HH];
    __shared__ float bias[8];

    const int u  = threadIdx.x;
    const int g  = blockIdx.x;
    const int j0 = g << 1;

    // ---- one-time staging of this block's weight slice ----
    for (int r = 0; r < 8; ++r) {
        const int R = (r >> 1) * HH + j0 + (r & 1);   // global gate row
        for (int k = u; k < KK; k += NTHR)
            Wl[r][k] = (k < II) ? W_ih[(size_t)R * II + k]
                                : W_hh[(size_t)R * HH + (k - II)];
    }
    if (u < 8) {
        const int R = (u >> 1) * HH + j0 + (u & 1);
        bias[u] = b_ih[R] + b_hh[R];
    }
    for (int k = u; k < HH; k += NTHR) wfc[k] = W_fc[k];
    if (u < BB) { cl[0][u] = 0.f; cl[1][u] = 0.f; }
    // zero this block's slice of h buffer 0 (buffer 1 is fully written at t=0)
    if (u < BB) {
        hbuf[(size_t)u * HH + j0]     = 0.f;
        hbuf[(size_t)u * HH + j0 + 1] = 0.f;
    }

    const float bfc  = b_fc[0];
    const bool  doy  = (g == 0);
    const int   bA   = u & 63, bB = bA + 64;   // lane -> batch rows (stride-64 split: bank-friendly)
    const int   rp   = u >> 6;                 // wave id = gate id
    const int   rA   = rp << 1, rB = rA + 1;   // local rows (gate, jj=0/1)

    cg::this_grid().sync();

    for (int t = 0; t <= TT; ++t) {
        const float* __restrict__ hsrc = hbuf + (size_t)(t & 1) * BB * HH;
        float*       __restrict__ hdst = hbuf + (size_t)((t + 1) & 1) * BB * HH;

        float a00 = 0.f, a01 = 0.f, a10 = 0.f, a11 = 0.f; // [rA,rB] x [bA,bB]
        float yacc = 0.f;

        const int ch0 = (t == TT) ? 1 : 0;   // last iter: y-tail only, no x
        for (int ch = ch0; ch < 9; ++ch) {
            // ---- stage one 64-wide k-chunk for all 128 batch rows ----
            if (ch == 0) {
                #pragma unroll
                for (int r8 = 0; r8 < 8; ++r8) {
                    const int flat = u + NTHR * r8;          // 0..2047
                    const int b = flat >> 4, q = flat & 15;  // 16 float4 per row
                    const float4 v = *(const float4*)(x + ((size_t)b * TT + t) * II + (q << 2));
                    *(float4*)&vx[b][q << 2] = v;
                }
            } else {
                const int k0 = (ch - 1) << 6;
                #pragma unroll
                for (int r8 = 0; r8 < 8; ++r8) {
                    const int flat = u + NTHR * r8;
                    const int b = flat >> 4, q = flat & 15;
                    const float4 v = *(const float4*)(hsrc + (size_t)b * HH + k0 + (q << 2));
                    *(float4*)&vx[b][q << 2] = v;
                }
            }
            __syncthreads();

            // ---- gate dots: 2 rows x 2 batch per thread, float4 ----
            if (t < TT) {
                const float* __restrict__ wra = &Wl[rA][ch << 6];
                const float* __restrict__ wrb = &Wl[rB][ch << 6];
                const float* __restrict__ va  = &vx[bA][0];
                const float* __restrict__ vb  = &vx[bB][0];
                #pragma unroll
                for (int k4 = 0; k4 < 16; ++k4) {
                    const float4 wa = *(const float4*)(wra + (k4 << 2));
                    const float4 wb = *(const float4*)(wrb + (k4 << 2));
                    const float4 pa = *(const float4*)(va + (k4 << 2));
                    const float4 pb = *(const float4*)(vb + (k4 << 2));
                    a00 += wa.x*pa.x + wa.y*pa.y + wa.z*pa.z + wa.w*pa.w;
                    a01 += wa.x*pb.x + wa.y*pb.y + wa.z*pb.z + wa.w*pb.w;
                    a10 += wb.x*pa.x + wb.y*pa.y + wb.z*pa.z + wb.w*pa.w;
                    a11 += wb.x*pb.x + wb.y*pb.y + wb.z*pb.z + wb.w*pb.w;
                }
            }
            // ---- y partial from staged h (block 0, one step delayed) ----
            if (doy && t > 0 && ch > 0) {
                const int b = u & 127, half = u >> 7;
                const float* __restrict__ wf = &wfc[((ch - 1) << 6) + (half << 5)];
                const float* __restrict__ vv = &vx[b][half << 5];
                #pragma unroll
                for (int k4 = 0; k4 < 8; ++k4) {
                    const float4 f4 = *(const float4*)(wf + (k4 << 2));
                    const float4 v4 = *(const float4*)(vv + (k4 << 2));
                    yacc += f4.x*v4.x + f4.y*v4.y + f4.z*v4.z + f4.w*v4.w;
                }
            }
            __syncthreads();
        }

        if (doy && t > 0) {
            const int b = u & 127, half = u >> 7;
            yl[half][b] = yacc;
        }

        if (t == TT) {  // final output column, then done (no more syncs needed)
            __syncthreads();
            if (doy && u < BB) out[(size_t)u * TT + (TT - 1)] = yl[0][u] + yl[1][u] + bfc;
            break;
        }

        gl[rA][bA] = a00 + bias[rA];
        gl[rA][bB] = a01 + bias[rA];
        gl[rB][bA] = a10 + bias[rB];
        gl[rB][bB] = a11 + bias[rB];
        __syncthreads();

        {   // c/h update: 256 threads cover (128 b) x (2 jj)
            const int b = u & 127, jj = u >> 7;
            const float gi = gl[0 + jj][b];
            const float gf = gl[2 + jj][b];
            const float gg = gl[4 + jj][b];
            const float go = gl[6 + jj][b];
            const float si = 1.f / (1.f + expf(-gi));
            const float sf = 1.f / (1.f + expf(-gf));
            const float tg = tanhf(gg);
            const float so = 1.f / (1.f + expf(-go));
            const float c  = sf * cl[jj][b] + si * tg;
            cl[jj][b] = c;
            hdst[(size_t)b * HH + j0 + jj] = so * tanhf(c);
            if (doy && t > 0 && u < BB)
                out[(size_t)u * TT + (t - 1)] = yl[0][u] + yl[1][u] + bfc;
        }

        __threadfence();
        cg::this_grid().sync();
    }
}

extern "C" void kernel_launch(void* const* d_in, const int* in_sizes, int n_in,
                              void* d_out, int out_size, void* d_ws, size_t ws_size,
                              hipStream_t stream) {
    const float* x    = (const float*)d_in[0];
    const float* W_ih = (const float*)d_in[1];
    const float* W_hh = (const float*)d_in[2];
    const float* b_ih = (const float*)d_in[3];
    const float* b_hh = (const float*)d_in[4];
    const float* W_fc = (const float*)d_in[5];
    const float* b_fc = (const float*)d_in[6];
    float* out  = (float*)d_out;
    float* hbuf = (float*)d_ws;   // 2 * 128 * 512 * 4B = 512 KB

    void* args[] = {(void*)&x, (void*)&W_ih, (void*)&W_hh, (void*)&b_ih,
                    (void*)&b_hh, (void*)&W_fc, (void*)&b_fc, (void*)&out,
                    (void*)&hbuf};
    hipLaunchCooperativeKernel((const void*)lstm_persist, dim3(NBLK), dim3(NTHR),
                               args, 0, stream);
}